// Round 1
// baseline (3479.856 us; speedup 1.0000x reference)
//
#include <hip/hip_runtime.h>

#define DIM 96
#define CHUNKS 24  // DIM / 4

// ---------------------------------------------------------------------------
// deg[row[e]] += 1 over all edges
__global__ void deg_kernel(const int* __restrict__ row, int E, float* __restrict__ deg) {
    int e = blockIdx.x * blockDim.x + threadIdx.x;
    if (e < E) atomicAdd(&deg[row[e]], 1.0f);
}

// deg -> dinv in place: dinv = deg > 0 ? rsqrt(deg) : 0
__global__ void dinv_kernel(float* deg, int N) {
    int i = blockIdx.x * blockDim.x + threadIdx.x;
    if (i < N) {
        float d = deg[i];
        deg[i] = (d > 0.0f) ? rsqrtf(d) : 0.0f;
    }
}

// out[i] = -in[i]  (works in place), float4-vectorized
__global__ void negcopy_kernel(const float4* __restrict__ in, float4* __restrict__ out, int n4) {
    int i = blockIdx.x * blockDim.x + threadIdx.x;
    if (i < n4) {
        float4 v = in[i];
        out[i] = make_float4(-v.x, -v.y, -v.z, -v.w);
    }
}

// dst[row[e]][:] += scale * norm[e] * h[col[e]][:]   (norm = -dinv[row]*dinv[col])
// thread = (edge, 4-feature chunk)
__global__ void scatter_kernel(const int* __restrict__ row, const int* __restrict__ col,
                               const float* __restrict__ dinv, const float* __restrict__ h,
                               float* __restrict__ dst, int E, float scale) {
    int tid = blockIdx.x * blockDim.x + threadIdx.x;
    if (tid >= E * CHUNKS) return;
    int e = tid / CHUNKS;
    int c = tid % CHUNKS;
    int r = row[e];
    int s = col[e];
    float nrm = -dinv[r] * dinv[s] * scale;
    const float4 v = *reinterpret_cast<const float4*>(h + (size_t)s * DIM + (size_t)c * 4);
    float* d = dst + (size_t)r * DIM + (size_t)c * 4;
    atomicAdd(d + 0, nrm * v.x);
    atomicAdd(d + 1, nrm * v.y);
    atomicAdd(d + 2, nrm * v.z);
    atomicAdd(d + 3, nrm * v.w);
}

// out[i][j] = bias[j] + sum_d T[i][d] * W[d][j]      (fresh write)
__global__ void gemm_bias_kernel(const float* __restrict__ T, const float* __restrict__ W,
                                 const float* __restrict__ bias, float* __restrict__ out, int N) {
    int tid = blockIdx.x * blockDim.x + threadIdx.x;
    if (tid >= N * DIM) return;
    int i = tid / DIM;
    int j = tid % DIM;
    const float* trow = T + (size_t)i * DIM;
    float acc = bias[j];
#pragma unroll
    for (int d = 0; d < DIM; ++d) acc = fmaf(trow[d], W[d * DIM + j], acc);
    out[tid] = acc;
}

// out[i][j] += sum_d T[i][d] * W[d][j]
__global__ void gemm_acc_kernel(const float* __restrict__ T, const float* __restrict__ W,
                                float* __restrict__ out, int N) {
    int tid = blockIdx.x * blockDim.x + threadIdx.x;
    if (tid >= N * DIM) return;
    int i = tid / DIM;
    int j = tid % DIM;
    const float* trow = T + (size_t)i * DIM;
    float acc = 0.0f;
#pragma unroll
    for (int d = 0; d < DIM; ++d) acc = fmaf(trow[d], W[d * DIM + j], acc);
    out[tid] += acc;
}

extern "C" void kernel_launch(void* const* d_in, const int* in_sizes, int n_in,
                              void* d_out, int out_size, void* d_ws, size_t ws_size,
                              hipStream_t stream) {
    const float* x    = (const float*)d_in[0];
    const int*   ei   = (const int*)d_in[1];
    const float* w    = (const float*)d_in[2];
    const float* bias = (const float*)d_in[3];
    float* out = (float*)d_out;

    const int N = in_sizes[0] / DIM;        // 50000
    const int E = in_sizes[1] / 2;          // 800000
    const int* row = ei;
    const int* col = ei + E;

    // workspace layout
    float* dinv = (float*)d_ws;                       // N floats (rounded up)
    size_t dinv_elems = (size_t)((N + 3) & ~3);
    float* T1 = dinv + dinv_elems;                    // N*DIM floats
    float* T2 = T1 + (size_t)N * DIM;                 // N*DIM floats

    const int BLK = 256;
    const int grid_edges   = (E + BLK - 1) / BLK;
    const int grid_nodes   = (N + BLK - 1) / BLK;
    const int grid_scatter = (int)(((long long)E * CHUNKS + BLK - 1) / BLK);
    const int grid_out     = (N * DIM + BLK - 1) / BLK;
    const int grid_neg     = ((N * DIM / 4) + BLK - 1) / BLK;

    // degree -> dinv
    hipMemsetAsync(dinv, 0, (size_t)N * sizeof(float), stream);
    deg_kernel<<<grid_edges, BLK, 0, stream>>>(row, E, dinv);
    dinv_kernel<<<grid_nodes, BLK, 0, stream>>>(dinv, N);

    // k = 0: out = x @ W0 + bias
    gemm_bias_kernel<<<grid_out, BLK, 0, stream>>>(x, w, bias, out, N);

    // k = 1: T1 = L_hat @ x ; out += T1 @ W1
    hipMemsetAsync(T1, 0, (size_t)N * DIM * sizeof(float), stream);
    scatter_kernel<<<grid_scatter, BLK, 0, stream>>>(row, col, dinv, x, T1, E, 1.0f);
    gemm_acc_kernel<<<grid_out, BLK, 0, stream>>>(T1, w + 1 * DIM * DIM, out, N);

    // k = 2: T2 = 2 * L_hat @ T1 - x ; out += T2 @ W2
    negcopy_kernel<<<grid_neg, BLK, 0, stream>>>((const float4*)x, (float4*)T2, N * DIM / 4);
    scatter_kernel<<<grid_scatter, BLK, 0, stream>>>(row, col, dinv, T1, T2, E, 2.0f);
    gemm_acc_kernel<<<grid_out, BLK, 0, stream>>>(T2, w + 2 * DIM * DIM, out, N);

    // k = 3: T3 (into T1 buffer) = 2 * L_hat @ T2 - T1 ; out += T3 @ W3
    negcopy_kernel<<<grid_neg, BLK, 0, stream>>>((const float4*)T1, (float4*)T1, N * DIM / 4);
    scatter_kernel<<<grid_scatter, BLK, 0, stream>>>(row, col, dinv, T2, T1, E, 2.0f);
    gemm_acc_kernel<<<grid_out, BLK, 0, stream>>>(T1, w + 3 * DIM * DIM, out, N);
}

// Round 2
// 772.308 us; speedup vs baseline: 4.5058x; 4.5058x over previous
//
#include <hip/hip_runtime.h>

#define DIM 96
#define CHUNKS 24   // DIM / 4 float4 chunks per node row
#define GBLK 192    // 8 nodes per block in gather

// ---------------------------------------------------------------------------
// integer degree histogram: degi[row[e]] += 1
__global__ void deg_kernel(const int* __restrict__ row, int E, int* __restrict__ degi) {
    int e = blockIdx.x * blockDim.x + threadIdx.x;
    if (e < E) atomicAdd(&degi[row[e]], 1);
}

// dinv[i] = degi[i] > 0 ? rsqrt(degi[i]) : 0
__global__ void dinv_kernel(const int* __restrict__ degi, float* __restrict__ dinv, int N) {
    int i = blockIdx.x * blockDim.x + threadIdx.x;
    if (i < N) {
        int d = degi[i];
        dinv[i] = (d > 0) ? rsqrtf((float)d) : 0.0f;
    }
}

// single-workgroup exclusive scan of degi -> offsets[0..N]
__global__ void scan_kernel(const int* __restrict__ degi, int* __restrict__ offsets, int N) {
    __shared__ int smem[1024];
    __shared__ int running;
    if (threadIdx.x == 0) running = 0;
    __syncthreads();
    for (int base = 0; base < N; base += 1024) {
        int i = base + threadIdx.x;
        int v = (i < N) ? degi[i] : 0;
        smem[threadIdx.x] = v;
        __syncthreads();
        for (int off = 1; off < 1024; off <<= 1) {
            int t = (threadIdx.x >= off) ? smem[threadIdx.x - off] : 0;
            __syncthreads();
            smem[threadIdx.x] += t;
            __syncthreads();
        }
        int incl = smem[threadIdx.x];
        int r = running;
        if (i < N) offsets[i] = r + incl - v;   // exclusive prefix
        int blocktotal = smem[1023];
        __syncthreads();
        if (threadIdx.x == 0) running = r + blocktotal;
        __syncthreads();
    }
    if (threadIdx.x == 0) offsets[N] = running;
}

// place each edge into its row segment; store col and dinv[col] weight
__global__ void build_csr_kernel(const int* __restrict__ row, const int* __restrict__ col,
                                 const float* __restrict__ dinv, const int* __restrict__ offsets,
                                 int* __restrict__ fill, int* __restrict__ colsorted,
                                 float* __restrict__ wsorted, int E) {
    int e = blockIdx.x * blockDim.x + threadIdx.x;
    if (e >= E) return;
    int r = row[e];
    int p = offsets[r] + atomicAdd(&fill[r], 1);
    int c = col[e];
    colsorted[p] = c;
    wsorted[p] = dinv[c];
}

// dst[i][:] = -scale * dinv[i] * sum_{e in row i} wsorted[e] * h[colsorted[e]][:]  (- prev[i][:])
// 24 threads per node, each owns one float4 chunk.
__global__ void gather_kernel(const int* __restrict__ offsets, const int* __restrict__ colsorted,
                              const float* __restrict__ wsorted, const float* __restrict__ dinv,
                              const float* __restrict__ h, const float* __restrict__ prev,
                              float* __restrict__ dst, int N, float scale) {
    int tid = blockIdx.x * blockDim.x + threadIdx.x;
    int node = tid / CHUNKS;
    int c = tid % CHUNKS;
    if (node >= N) return;
    int s = offsets[node];
    int e = offsets[node + 1];
    float ax = 0.f, ay = 0.f, az = 0.f, aw = 0.f;
    for (int k = s; k < e; ++k) {
        int src = colsorted[k];
        float w0 = wsorted[k];
        const float4 v = *reinterpret_cast<const float4*>(h + (size_t)src * DIM + c * 4);
        ax = fmaf(w0, v.x, ax);
        ay = fmaf(w0, v.y, ay);
        az = fmaf(w0, v.z, az);
        aw = fmaf(w0, v.w, aw);
    }
    float m = -scale * dinv[node];
    float4 o = make_float4(m * ax, m * ay, m * az, m * aw);
    if (prev) {
        const float4 p = *reinterpret_cast<const float4*>(prev + (size_t)node * DIM + c * 4);
        o.x -= p.x; o.y -= p.y; o.z -= p.z; o.w -= p.w;
    }
    *reinterpret_cast<float4*>(dst + (size_t)node * DIM + c * 4) = o;
}

// out[i][j] = bias[j] + sum_d T[i][d] * W[d][j]
__global__ void gemm_bias_kernel(const float* __restrict__ T, const float* __restrict__ W,
                                 const float* __restrict__ bias, float* __restrict__ out, int N) {
    int tid = blockIdx.x * blockDim.x + threadIdx.x;
    if (tid >= N * DIM) return;
    int i = tid / DIM;
    int j = tid % DIM;
    const float* trow = T + (size_t)i * DIM;
    float acc = bias[j];
#pragma unroll
    for (int d = 0; d < DIM; ++d) acc = fmaf(trow[d], W[d * DIM + j], acc);
    out[tid] = acc;
}

// out[i][j] += sum_d T[i][d] * W[d][j]
__global__ void gemm_acc_kernel(const float* __restrict__ T, const float* __restrict__ W,
                                float* __restrict__ out, int N) {
    int tid = blockIdx.x * blockDim.x + threadIdx.x;
    if (tid >= N * DIM) return;
    int i = tid / DIM;
    int j = tid % DIM;
    const float* trow = T + (size_t)i * DIM;
    float acc = 0.0f;
#pragma unroll
    for (int d = 0; d < DIM; ++d) acc = fmaf(trow[d], W[d * DIM + j], acc);
    out[tid] += acc;
}

extern "C" void kernel_launch(void* const* d_in, const int* in_sizes, int n_in,
                              void* d_out, int out_size, void* d_ws, size_t ws_size,
                              hipStream_t stream) {
    const float* x    = (const float*)d_in[0];
    const int*   ei   = (const int*)d_in[1];
    const float* w    = (const float*)d_in[2];
    const float* bias = (const float*)d_in[3];
    float* out = (float*)d_out;

    const int N = in_sizes[0] / DIM;   // 50000
    const int E = in_sizes[1] / 2;     // 800000
    const int* row = ei;
    const int* col = ei + E;

    // ---- workspace layout (all 16B-aligned chunks) ----
    char* p = (char*)d_ws;
    auto alloc = [&](size_t bytes) { char* q = p; p += (bytes + 15) & ~(size_t)15; return q; };
    int*   degi      = (int*)  alloc((size_t)N * 4);        // degree, reused as fill counter
    int*   offsets   = (int*)  alloc((size_t)(N + 1) * 4);
    float* dinv      = (float*)alloc((size_t)N * 4);
    int*   colsorted = (int*)  alloc((size_t)E * 4);
    float* wsorted   = (float*)alloc((size_t)E * 4);
    float* T1        = (float*)alloc((size_t)N * DIM * 4);
    float* T2        = (float*)alloc((size_t)N * DIM * 4);

    const int BLK = 256;
    const int grid_edges  = (E + BLK - 1) / BLK;
    const int grid_nodes  = (N + BLK - 1) / BLK;
    const int grid_out    = (N * DIM + BLK - 1) / BLK;
    const int grid_gather = (N * CHUNKS + GBLK - 1) / GBLK;

    // ---- build normalized CSR ----
    hipMemsetAsync(degi, 0, (size_t)N * 4, stream);
    deg_kernel<<<grid_edges, BLK, 0, stream>>>(row, E, degi);
    dinv_kernel<<<grid_nodes, BLK, 0, stream>>>(degi, dinv, N);
    scan_kernel<<<1, 1024, 0, stream>>>(degi, offsets, N);
    hipMemsetAsync(degi, 0, (size_t)N * 4, stream);   // reuse as fill counters
    build_csr_kernel<<<grid_edges, BLK, 0, stream>>>(row, col, dinv, offsets, degi,
                                                     colsorted, wsorted, E);

    // ---- k = 0: out = x @ W0 + bias ----
    gemm_bias_kernel<<<grid_out, BLK, 0, stream>>>(x, w, bias, out, N);

    // ---- k = 1: T1 = L_hat @ x ; out += T1 @ W1 ----
    gather_kernel<<<grid_gather, GBLK, 0, stream>>>(offsets, colsorted, wsorted, dinv,
                                                    x, nullptr, T1, N, 1.0f);
    gemm_acc_kernel<<<grid_out, BLK, 0, stream>>>(T1, w + 1 * DIM * DIM, out, N);

    // ---- k = 2: T2 = 2*L_hat@T1 - x ; out += T2 @ W2 ----
    gather_kernel<<<grid_gather, GBLK, 0, stream>>>(offsets, colsorted, wsorted, dinv,
                                                    T1, x, T2, N, 2.0f);
    gemm_acc_kernel<<<grid_out, BLK, 0, stream>>>(T2, w + 2 * DIM * DIM, out, N);

    // ---- k = 3: T3 (into T1's slot... need T1 as prev, write to new buffer) ----
    // T3 = 2*L_hat@T2 - T1 ; write into a third region? Reuse: write into T1 is unsafe
    // (T1 is both prev input and would-be output read at different rows). gather reads
    // prev[node] and writes dst[node] for the same node only -> in-place vs prev is safe,
    // but h=T2 is a different buffer, so dst=T1 with prev=T1 is element-wise safe.
    gather_kernel<<<grid_gather, GBLK, 0, stream>>>(offsets, colsorted, wsorted, dinv,
                                                    T2, T1, T1, N, 2.0f);
    gemm_acc_kernel<<<grid_out, BLK, 0, stream>>>(T1, w + 3 * DIM * DIM, out, N);
}

// Round 3
// 451.851 us; speedup vs baseline: 7.7013x; 1.7092x over previous
//
#include <hip/hip_runtime.h>

#define DIM 96
#define CHUNKS 24   // DIM / 4 float4 chunks per node row
#define GBLK 192    // 8 nodes per block in gather
#define R_TILE 32   // rows per block in fused GEMM

// ---------------------------------------------------------------------------
// integer degree histogram: degi[row[e]] += 1
__global__ void deg_kernel(const int* __restrict__ row, int E, int* __restrict__ degi) {
    int e = blockIdx.x * blockDim.x + threadIdx.x;
    if (e < E) atomicAdd(&degi[row[e]], 1);
}

// dinv[i] = degi[i] > 0 ? rsqrt(degi[i]) : 0
__global__ void dinv_kernel(const int* __restrict__ degi, float* __restrict__ dinv, int N) {
    int i = blockIdx.x * blockDim.x + threadIdx.x;
    if (i < N) {
        int d = degi[i];
        dinv[i] = (d > 0) ? rsqrtf((float)d) : 0.0f;
    }
}

// single-workgroup exclusive scan of degi -> offsets[0..N]
__global__ void scan_kernel(const int* __restrict__ degi, int* __restrict__ offsets, int N) {
    __shared__ int smem[1024];
    __shared__ int running;
    if (threadIdx.x == 0) running = 0;
    __syncthreads();
    for (int base = 0; base < N; base += 1024) {
        int i = base + threadIdx.x;
        int v = (i < N) ? degi[i] : 0;
        smem[threadIdx.x] = v;
        __syncthreads();
        for (int off = 1; off < 1024; off <<= 1) {
            int t = (threadIdx.x >= off) ? smem[threadIdx.x - off] : 0;
            __syncthreads();
            smem[threadIdx.x] += t;
            __syncthreads();
        }
        int incl = smem[threadIdx.x];
        int r = running;
        if (i < N) offsets[i] = r + incl - v;   // exclusive prefix
        int blocktotal = smem[1023];
        __syncthreads();
        if (threadIdx.x == 0) running = r + blocktotal;
        __syncthreads();
    }
    if (threadIdx.x == 0) offsets[N] = running;
}

// place each edge into its row segment; store col and dinv[col] weight
__global__ void build_csr_kernel(const int* __restrict__ row, const int* __restrict__ col,
                                 const float* __restrict__ dinv, const int* __restrict__ offsets,
                                 int* __restrict__ fill, int* __restrict__ colsorted,
                                 float* __restrict__ wsorted, int E) {
    int e = blockIdx.x * blockDim.x + threadIdx.x;
    if (e >= E) return;
    int r = row[e];
    int p = offsets[r] + atomicAdd(&fill[r], 1);
    int c = col[e];
    colsorted[p] = c;
    wsorted[p] = dinv[c];
}

// dst[i][:] = -scale * dinv[i] * sum_{e in row i} wsorted[e] * h[colsorted[e]][:]  (- prev[i][:])
// 24 threads per node, each owns one float4 chunk.
__global__ void gather_kernel(const int* __restrict__ offsets, const int* __restrict__ colsorted,
                              const float* __restrict__ wsorted, const float* __restrict__ dinv,
                              const float* __restrict__ h, const float* __restrict__ prev,
                              float* __restrict__ dst, int N, float scale) {
    int tid = blockIdx.x * blockDim.x + threadIdx.x;
    int node = tid / CHUNKS;
    int c = tid % CHUNKS;
    if (node >= N) return;
    int s = offsets[node];
    int e = offsets[node + 1];
    float ax = 0.f, ay = 0.f, az = 0.f, aw = 0.f;
    for (int k = s; k < e; ++k) {
        int src = colsorted[k];
        float w0 = wsorted[k];
        const float4 v = *reinterpret_cast<const float4*>(h + (size_t)src * DIM + c * 4);
        ax = fmaf(w0, v.x, ax);
        ay = fmaf(w0, v.y, ay);
        az = fmaf(w0, v.z, az);
        aw = fmaf(w0, v.w, aw);
    }
    float m = -scale * dinv[node];
    float4 o = make_float4(m * ax, m * ay, m * az, m * aw);
    if (prev) {
        const float4 p = *reinterpret_cast<const float4*>(prev + (size_t)node * DIM + c * 4);
        o.x -= p.x; o.y -= p.y; o.z -= p.z; o.w -= p.w;
    }
    *reinterpret_cast<float4*>(dst + (size_t)node * DIM + c * 4) = o;
}

// Fused two-matrix GEMM: out[i][:] (=|+=) A[i][:]@W0 + B[i][:]@W1 (+ bias)
// 192 threads, 32-row tile staged in LDS, each thread 4 rows x 4 cols.
__global__ __launch_bounds__(192) void gemm2_kernel(
        const float* __restrict__ A, const float* __restrict__ B,
        const float* __restrict__ W0, const float* __restrict__ W1,
        const float* __restrict__ bias, float* __restrict__ out, int N, int accumulate) {
    __shared__ float sA[R_TILE][DIM + 1];
    __shared__ float sB[R_TILE][DIM + 1];
    const int tid = threadIdx.x;
    const int row0 = blockIdx.x * R_TILE;

    // cooperative load of A/B tiles (float4 granularity)
    for (int l = tid; l < R_TILE * CHUNKS; l += 192) {
        int r = l / CHUNKS;
        int cq = l % CHUNKS;
        int g = row0 + r;
        float4 va = make_float4(0.f, 0.f, 0.f, 0.f);
        float4 vb = va;
        if (g < N) {
            va = *reinterpret_cast<const float4*>(A + (size_t)g * DIM + cq * 4);
            vb = *reinterpret_cast<const float4*>(B + (size_t)g * DIM + cq * 4);
        }
        sA[r][cq * 4 + 0] = va.x; sA[r][cq * 4 + 1] = va.y;
        sA[r][cq * 4 + 2] = va.z; sA[r][cq * 4 + 3] = va.w;
        sB[r][cq * 4 + 0] = vb.x; sB[r][cq * 4 + 1] = vb.y;
        sB[r][cq * 4 + 2] = vb.z; sB[r][cq * 4 + 3] = vb.w;
    }
    __syncthreads();

    const int cq = tid % CHUNKS;       // col chunk 0..23
    const int r0 = tid / CHUNKS;       // row slot 0..7
    float4 acc[4];
#pragma unroll
    for (int rr = 0; rr < 4; ++rr) acc[rr] = make_float4(0.f, 0.f, 0.f, 0.f);

    for (int d = 0; d < DIM; ++d) {
        const float4 w0 = *reinterpret_cast<const float4*>(W0 + d * DIM + cq * 4);
        const float4 w1 = *reinterpret_cast<const float4*>(W1 + d * DIM + cq * 4);
#pragma unroll
        for (int rr = 0; rr < 4; ++rr) {
            const int r = r0 + rr * 8;
            float a = sA[r][d];
            float b = sB[r][d];
            acc[rr].x = fmaf(a, w0.x, acc[rr].x);
            acc[rr].y = fmaf(a, w0.y, acc[rr].y);
            acc[rr].z = fmaf(a, w0.z, acc[rr].z);
            acc[rr].w = fmaf(a, w0.w, acc[rr].w);
            acc[rr].x = fmaf(b, w1.x, acc[rr].x);
            acc[rr].y = fmaf(b, w1.y, acc[rr].y);
            acc[rr].z = fmaf(b, w1.z, acc[rr].z);
            acc[rr].w = fmaf(b, w1.w, acc[rr].w);
        }
    }

    const float4 b4 = *reinterpret_cast<const float4*>(bias + cq * 4);
#pragma unroll
    for (int rr = 0; rr < 4; ++rr) {
        const int g = row0 + r0 + rr * 8;
        if (g >= N) continue;
        float4 o = acc[rr];
        float* dst = out + (size_t)g * DIM + cq * 4;
        if (accumulate) {
            float4 p = *reinterpret_cast<const float4*>(dst);
            o.x += p.x; o.y += p.y; o.z += p.z; o.w += p.w;
        } else {
            o.x += b4.x; o.y += b4.y; o.z += b4.z; o.w += b4.w;
        }
        *reinterpret_cast<float4*>(dst) = o;
    }
}

extern "C" void kernel_launch(void* const* d_in, const int* in_sizes, int n_in,
                              void* d_out, int out_size, void* d_ws, size_t ws_size,
                              hipStream_t stream) {
    const float* x    = (const float*)d_in[0];
    const int*   ei   = (const int*)d_in[1];
    const float* w    = (const float*)d_in[2];
    const float* bias = (const float*)d_in[3];
    float* out = (float*)d_out;

    const int N = in_sizes[0] / DIM;   // 50000
    const int E = in_sizes[1] / 2;     // 800000
    const int* row = ei;
    const int* col = ei + E;

    // ---- workspace layout ----
    char* p = (char*)d_ws;
    auto alloc = [&](size_t bytes) { char* q = p; p += (bytes + 15) & ~(size_t)15; return q; };
    int*   degi      = (int*)  alloc((size_t)N * 4);        // degree, reused as fill counter
    int*   offsets   = (int*)  alloc((size_t)(N + 1) * 4);
    float* dinv      = (float*)alloc((size_t)N * 4);
    int*   colsorted = (int*)  alloc((size_t)E * 4);
    float* wsorted   = (float*)alloc((size_t)E * 4);
    float* T1        = (float*)alloc((size_t)N * DIM * 4);
    float* T2        = (float*)alloc((size_t)N * DIM * 4);

    const int BLK = 256;
    const int grid_edges  = (E + BLK - 1) / BLK;
    const int grid_nodes  = (N + BLK - 1) / BLK;
    const int grid_gather = (N * CHUNKS + GBLK - 1) / GBLK;
    const int grid_gemm   = (N + R_TILE - 1) / R_TILE;

    // ---- build normalized CSR ----
    hipMemsetAsync(degi, 0, (size_t)N * 4, stream);
    deg_kernel<<<grid_edges, BLK, 0, stream>>>(row, E, degi);
    dinv_kernel<<<grid_nodes, BLK, 0, stream>>>(degi, dinv, N);
    scan_kernel<<<1, 1024, 0, stream>>>(degi, offsets, N);
    hipMemsetAsync(degi, 0, (size_t)N * 4, stream);   // reuse as fill counters
    build_csr_kernel<<<grid_edges, BLK, 0, stream>>>(row, col, dinv, offsets, degi,
                                                     colsorted, wsorted, E);

    // ---- hops ----
    // T1 = L_hat @ x
    gather_kernel<<<grid_gather, GBLK, 0, stream>>>(offsets, colsorted, wsorted, dinv,
                                                    x, nullptr, T1, N, 1.0f);
    // T2 = 2*L_hat@T1 - x
    gather_kernel<<<grid_gather, GBLK, 0, stream>>>(offsets, colsorted, wsorted, dinv,
                                                    T1, x, T2, N, 2.0f);
    // pass A: out = bias + x@W0 + T1@W1
    gemm2_kernel<<<grid_gemm, 192, 0, stream>>>(x, T1, w + 0 * DIM * DIM, w + 1 * DIM * DIM,
                                                bias, out, N, 0);
    // T3 (in place into T1) = 2*L_hat@T2 - T1   (element-wise in-place vs prev: safe)
    gather_kernel<<<grid_gather, GBLK, 0, stream>>>(offsets, colsorted, wsorted, dinv,
                                                    T2, T1, T1, N, 2.0f);
    // pass B: out += T2@W2 + T3@W3
    gemm2_kernel<<<grid_gemm, 192, 0, stream>>>(T2, T1, w + 2 * DIM * DIM, w + 3 * DIM * DIM,
                                                bias, out, N, 1);
}

// Round 4
// 372.159 us; speedup vs baseline: 9.3505x; 1.2141x over previous
//
#include <hip/hip_runtime.h>

#define DIM 96
#define CHUNKS 24   // DIM / 4 float4 chunks per node row
#define GBLK 192    // 8 nodes per block in gather
#define R_TILE 32   // rows per block in fused GEMM
#define SCAN_CHUNK 1024  // elements per block in phase-1 scan

// ---------------------------------------------------------------------------
// integer degree histogram: degi[row[e]] += 1
__global__ void deg_kernel(const int* __restrict__ row, int E, int* __restrict__ degi) {
    int e = blockIdx.x * blockDim.x + threadIdx.x;
    if (e < E) atomicAdd(&degi[row[e]], 1);
}

// dinv[i] = degi[i] > 0 ? rsqrt(degi[i]) : 0
__global__ void dinv_kernel(const int* __restrict__ degi, float* __restrict__ dinv, int N) {
    int i = blockIdx.x * blockDim.x + threadIdx.x;
    if (i < N) {
        int d = degi[i];
        dinv[i] = (d > 0) ? rsqrtf((float)d) : 0.0f;
    }
}

// ---- multi-block exclusive scan of degi -> offsets ----
// phase 1: per-block scan of SCAN_CHUNK elements (4/thread), write exclusive
// partials into offsets[] and the block total into blocksums[b]
__global__ __launch_bounds__(256) void scan_blocks_kernel(
        const int* __restrict__ degi, int* __restrict__ offsets,
        int* __restrict__ blocksums, int N) {
    __shared__ int s[256];
    const int t = threadIdx.x;
    const int base = blockIdx.x * SCAN_CHUNK + t * 4;
    int v0 = 0, v1 = 0, v2 = 0, v3 = 0;
    if (base + 3 < N) {
        const int4 q = *reinterpret_cast<const int4*>(degi + base);
        v0 = q.x; v1 = q.y; v2 = q.z; v3 = q.w;
    } else {
        if (base + 0 < N) v0 = degi[base + 0];
        if (base + 1 < N) v1 = degi[base + 1];
        if (base + 2 < N) v2 = degi[base + 2];
        if (base + 3 < N) v3 = degi[base + 3];
    }
    const int mysum = v0 + v1 + v2 + v3;
    s[t] = mysum;
    __syncthreads();
    for (int off = 1; off < 256; off <<= 1) {
        int x = (t >= off) ? s[t - off] : 0;
        __syncthreads();
        s[t] += x;
        __syncthreads();
    }
    int run = s[t] - mysum;   // exclusive prefix of this thread's 4-group
    if (t == 255) blocksums[blockIdx.x] = s[255];
    if (base + 0 < N) offsets[base + 0] = run;  run += v0;
    if (base + 1 < N) offsets[base + 1] = run;  run += v1;
    if (base + 2 < N) offsets[base + 2] = run;  run += v2;
    if (base + 3 < N) offsets[base + 3] = run;
}

// phase 2: single block exclusive-scans blocksums in place (nb <= 256)
__global__ __launch_bounds__(256) void scan_sums_kernel(int* __restrict__ blocksums, int nb) {
    __shared__ int s[256];
    const int t = threadIdx.x;
    const int v = (t < nb) ? blocksums[t] : 0;
    s[t] = v;
    __syncthreads();
    for (int off = 1; off < 256; off <<= 1) {
        int x = (t >= off) ? s[t - off] : 0;
        __syncthreads();
        s[t] += x;
        __syncthreads();
    }
    if (t < nb) blocksums[t] = s[t] - v;   // exclusive
}

// phase 3: add block bases; also write offsets[N] = E (known analytically)
__global__ __launch_bounds__(256) void scan_add_kernel(
        int* __restrict__ offsets, const int* __restrict__ blocksums, int N, int E) {
    const int i = blockIdx.x * blockDim.x + threadIdx.x;
    if (i < N) offsets[i] += blocksums[i >> 10];  // SCAN_CHUNK == 1024
    if (i == 0) offsets[N] = E;
}

// place each edge into its row segment; store col and dinv[col] weight
__global__ void build_csr_kernel(const int* __restrict__ row, const int* __restrict__ col,
                                 const float* __restrict__ dinv, const int* __restrict__ offsets,
                                 int* __restrict__ fill, int* __restrict__ colsorted,
                                 float* __restrict__ wsorted, int E) {
    int e = blockIdx.x * blockDim.x + threadIdx.x;
    if (e >= E) return;
    int r = row[e];
    int p = offsets[r] + atomicAdd(&fill[r], 1);
    int c = col[e];
    colsorted[p] = c;
    wsorted[p] = dinv[c];
}

// dst[i][:] = -scale * dinv[i] * sum_{e in row i} wsorted[e] * h[colsorted[e]][:]  (- prev[i][:])
// 24 threads per node, each owns one float4 chunk.
__global__ void gather_kernel(const int* __restrict__ offsets, const int* __restrict__ colsorted,
                              const float* __restrict__ wsorted, const float* __restrict__ dinv,
                              const float* __restrict__ h, const float* __restrict__ prev,
                              float* __restrict__ dst, int N, float scale) {
    int tid = blockIdx.x * blockDim.x + threadIdx.x;
    int node = tid / CHUNKS;
    int c = tid % CHUNKS;
    if (node >= N) return;
    int s = offsets[node];
    int e = offsets[node + 1];
    float ax = 0.f, ay = 0.f, az = 0.f, aw = 0.f;
    for (int k = s; k < e; ++k) {
        int src = colsorted[k];
        float w0 = wsorted[k];
        const float4 v = *reinterpret_cast<const float4*>(h + (size_t)src * DIM + c * 4);
        ax = fmaf(w0, v.x, ax);
        ay = fmaf(w0, v.y, ay);
        az = fmaf(w0, v.z, az);
        aw = fmaf(w0, v.w, aw);
    }
    float m = -scale * dinv[node];
    float4 o = make_float4(m * ax, m * ay, m * az, m * aw);
    if (prev) {
        const float4 p = *reinterpret_cast<const float4*>(prev + (size_t)node * DIM + c * 4);
        o.x -= p.x; o.y -= p.y; o.z -= p.z; o.w -= p.w;
    }
    *reinterpret_cast<float4*>(dst + (size_t)node * DIM + c * 4) = o;
}

// Fused two-matrix GEMM: out[i][:] (=|+=) A[i][:]@W0 + B[i][:]@W1 (+ bias)
// 192 threads, 32-row tile staged in LDS, each thread 4 rows x 4 cols.
__global__ __launch_bounds__(192) void gemm2_kernel(
        const float* __restrict__ A, const float* __restrict__ B,
        const float* __restrict__ W0, const float* __restrict__ W1,
        const float* __restrict__ bias, float* __restrict__ out, int N, int accumulate) {
    __shared__ float sA[R_TILE][DIM + 1];
    __shared__ float sB[R_TILE][DIM + 1];
    const int tid = threadIdx.x;
    const int row0 = blockIdx.x * R_TILE;

    for (int l = tid; l < R_TILE * CHUNKS; l += 192) {
        int r = l / CHUNKS;
        int cq = l % CHUNKS;
        int g = row0 + r;
        float4 va = make_float4(0.f, 0.f, 0.f, 0.f);
        float4 vb = va;
        if (g < N) {
            va = *reinterpret_cast<const float4*>(A + (size_t)g * DIM + cq * 4);
            vb = *reinterpret_cast<const float4*>(B + (size_t)g * DIM + cq * 4);
        }
        sA[r][cq * 4 + 0] = va.x; sA[r][cq * 4 + 1] = va.y;
        sA[r][cq * 4 + 2] = va.z; sA[r][cq * 4 + 3] = va.w;
        sB[r][cq * 4 + 0] = vb.x; sB[r][cq * 4 + 1] = vb.y;
        sB[r][cq * 4 + 2] = vb.z; sB[r][cq * 4 + 3] = vb.w;
    }
    __syncthreads();

    const int cq = tid % CHUNKS;       // col chunk 0..23
    const int r0 = tid / CHUNKS;       // row slot 0..7
    float4 acc[4];
#pragma unroll
    for (int rr = 0; rr < 4; ++rr) acc[rr] = make_float4(0.f, 0.f, 0.f, 0.f);

    for (int d = 0; d < DIM; ++d) {
        const float4 w0 = *reinterpret_cast<const float4*>(W0 + d * DIM + cq * 4);
        const float4 w1 = *reinterpret_cast<const float4*>(W1 + d * DIM + cq * 4);
#pragma unroll
        for (int rr = 0; rr < 4; ++rr) {
            const int r = r0 + rr * 8;
            float a = sA[r][d];
            float b = sB[r][d];
            acc[rr].x = fmaf(a, w0.x, acc[rr].x);
            acc[rr].y = fmaf(a, w0.y, acc[rr].y);
            acc[rr].z = fmaf(a, w0.z, acc[rr].z);
            acc[rr].w = fmaf(a, w0.w, acc[rr].w);
            acc[rr].x = fmaf(b, w1.x, acc[rr].x);
            acc[rr].y = fmaf(b, w1.y, acc[rr].y);
            acc[rr].z = fmaf(b, w1.z, acc[rr].z);
            acc[rr].w = fmaf(b, w1.w, acc[rr].w);
        }
    }

    const float4 b4 = *reinterpret_cast<const float4*>(bias + cq * 4);
#pragma unroll
    for (int rr = 0; rr < 4; ++rr) {
        const int g = row0 + r0 + rr * 8;
        if (g >= N) continue;
        float4 o = acc[rr];
        float* dst = out + (size_t)g * DIM + cq * 4;
        if (accumulate) {
            float4 p = *reinterpret_cast<const float4*>(dst);
            o.x += p.x; o.y += p.y; o.z += p.z; o.w += p.w;
        } else {
            o.x += b4.x; o.y += b4.y; o.z += b4.z; o.w += b4.w;
        }
        *reinterpret_cast<float4*>(dst) = o;
    }
}

extern "C" void kernel_launch(void* const* d_in, const int* in_sizes, int n_in,
                              void* d_out, int out_size, void* d_ws, size_t ws_size,
                              hipStream_t stream) {
    const float* x    = (const float*)d_in[0];
    const int*   ei   = (const int*)d_in[1];
    const float* w    = (const float*)d_in[2];
    const float* bias = (const float*)d_in[3];
    float* out = (float*)d_out;

    const int N = in_sizes[0] / DIM;   // 50000
    const int E = in_sizes[1] / 2;     // 800000
    const int* row = ei;
    const int* col = ei + E;

    // ---- workspace layout ----
    char* p = (char*)d_ws;
    auto alloc = [&](size_t bytes) { char* q = p; p += (bytes + 15) & ~(size_t)15; return q; };
    int*   degi      = (int*)  alloc((size_t)N * 4);        // degree, reused as fill counter
    int*   offsets   = (int*)  alloc((size_t)(N + 1) * 4);
    float* dinv      = (float*)alloc((size_t)N * 4);
    int*   blocksums = (int*)  alloc(256 * 4);
    int*   colsorted = (int*)  alloc((size_t)E * 4);
    float* wsorted   = (float*)alloc((size_t)E * 4);
    float* T1        = (float*)alloc((size_t)N * DIM * 4);
    float* T2        = (float*)alloc((size_t)N * DIM * 4);

    const int BLK = 256;
    const int grid_edges  = (E + BLK - 1) / BLK;
    const int grid_nodes  = (N + BLK - 1) / BLK;
    const int grid_gather = (N * CHUNKS + GBLK - 1) / GBLK;
    const int grid_gemm   = (N + R_TILE - 1) / R_TILE;
    const int nscan       = (N + SCAN_CHUNK - 1) / SCAN_CHUNK;   // 49 for N=50000

    // ---- build normalized CSR ----
    hipMemsetAsync(degi, 0, (size_t)N * 4, stream);
    deg_kernel<<<grid_edges, BLK, 0, stream>>>(row, E, degi);
    dinv_kernel<<<grid_nodes, BLK, 0, stream>>>(degi, dinv, N);
    scan_blocks_kernel<<<nscan, 256, 0, stream>>>(degi, offsets, blocksums, N);
    scan_sums_kernel<<<1, 256, 0, stream>>>(blocksums, nscan);
    scan_add_kernel<<<grid_nodes, 256, 0, stream>>>(offsets, blocksums, N, E);
    hipMemsetAsync(degi, 0, (size_t)N * 4, stream);   // reuse as fill counters
    build_csr_kernel<<<grid_edges, BLK, 0, stream>>>(row, col, dinv, offsets, degi,
                                                     colsorted, wsorted, E);

    // ---- hops + fused GEMMs ----
    gather_kernel<<<grid_gather, GBLK, 0, stream>>>(offsets, colsorted, wsorted, dinv,
                                                    x, nullptr, T1, N, 1.0f);
    gather_kernel<<<grid_gather, GBLK, 0, stream>>>(offsets, colsorted, wsorted, dinv,
                                                    T1, x, T2, N, 2.0f);
    gemm2_kernel<<<grid_gemm, 192, 0, stream>>>(x, T1, w + 0 * DIM * DIM, w + 1 * DIM * DIM,
                                                bias, out, N, 0);
    gather_kernel<<<grid_gather, GBLK, 0, stream>>>(offsets, colsorted, wsorted, dinv,
                                                    T2, T1, T1, N, 2.0f);
    gemm2_kernel<<<grid_gemm, 192, 0, stream>>>(T2, T1, w + 2 * DIM * DIM, w + 3 * DIM * DIM,
                                                bias, out, N, 1);
}